// Round 3
// baseline (5455.299 us; speedup 1.0000x reference)
//
#include <hip/hip_runtime.h>
#include <cstdint>

#define BH  16
#define SEQ 2048
#define DIM 64
#define OUT_ELEMS (BH*SEQ*DIM)   // 2097152 floats; attn follows at this offset

typedef float f32x4 __attribute__((ext_vector_type(4)));  // native vec for nontemporal builtin

// XOR swizzle on the S float index: perturb bits 2-4 with bits 5-7 so both the
// column-striped phases (stride 1 within a wave) and the PV phase
// (32-float c-partitions) are bank-conflict-free.
__device__ __forceinline__ int SW(int c){ return c ^ (((c >> 5) & 7) << 2); }

// ---------------- Kernel A1: partial M = k^T q  (per batch, per 128-row K chunk) ----
__global__ __launch_bounds__(256) void kA1(const float* __restrict__ kk,
                                           const float* __restrict__ qq,
                                           float* __restrict__ part){
  __shared__ __align__(16) float kl[64][68];
  __shared__ __align__(16) float ql[64][68];
  const int b   = blockIdx.y;
  const int ch  = blockIdx.x;          // 16 chunks of 128 rows
  const int tid = threadIdx.x;
  const int j     = tid & 63;          // e (q-col) index
  const int ibase = (tid >> 6) * 16;   // d (k-col) base
  const int lrow  = tid >> 2;
  const int lcol  = (tid & 3) * 16;
  const float* kb = kk + (size_t)b*SEQ*DIM;
  const float* qb = qq + (size_t)b*SEQ*DIM;
  float acc[16];
  #pragma unroll
  for (int i=0;i<16;i++) acc[i]=0.f;
  for (int sub=0; sub<2; ++sub){
    const int l0 = ch*128 + sub*64;
    const float4* ks = (const float4*)(kb + (size_t)(l0+lrow)*DIM + lcol);
    const float4* qs = (const float4*)(qb + (size_t)(l0+lrow)*DIM + lcol);
    float4 kv[4], qv[4];
    #pragma unroll
    for (int i=0;i<4;i++){ kv[i]=ks[i]; qv[i]=qs[i]; }
    __syncthreads();
    #pragma unroll
    for (int i=0;i<4;i++){
      *(float4*)&kl[lrow][lcol+4*i] = kv[i];
      *(float4*)&ql[lrow][lcol+4*i] = qv[i];
    }
    __syncthreads();
    for (int t=0; t<64; ++t){
      const float qv1 = ql[t][j];
      #pragma unroll
      for (int ii=0; ii<16; ++ii)
        acc[ii] += kl[t][ibase+ii] * qv1;
    }
  }
  float* pp = part + (size_t)(b*16+ch)*4096;
  #pragma unroll
  for (int ii=0; ii<16; ++ii)
    pp[(ibase+ii)*64 + j] = acc[ii];
}

// ---------------- Kernel A2: reduce partials, fold 1/temper^2 ----------------------
__global__ __launch_bounds__(256) void kA2(const float* __restrict__ part,
                                           float* __restrict__ M){
  const int idx = blockIdx.x*256 + threadIdx.x;   // 16*4096 = 65536
  const int b = idx >> 12, o = idx & 4095;
  float s = 0.f;
  #pragma unroll
  for (int ch=0; ch<16; ++ch)
    s += part[(size_t)(b*16+ch)*4096 + o];
  M[(size_t)b*4096 + o] = s * (1.0f/64.0f);
}

// ---------------- Kernel B: persistent, XCD-pinned batches -------------------------
// block i -> xcd i&7 -> batch xcd*2 + (slot&1); 32 blocks/batch, 8 row-group tasks each.
__global__ __launch_bounds__(512,4) void kB(const float* __restrict__ q,
                                            const float* __restrict__ pos,
                                            const float* __restrict__ v,
                                            const float* __restrict__ M,
                                            float* __restrict__ outp,
                                            float* __restrict__ attn){
  __shared__ __align__(16) float S[8][2048];      // 64 KB: M stage -> logits -> exp; red2 overlay
  __shared__ __align__(16) float Tt[8][64];
  __shared__ __align__(16) float qr[8][64];
  __shared__ float red[8][8];
  __shared__ float mrow[8];
  __shared__ float linv[8];

  const int blk   = blockIdx.x;
  const int xcd   = blk & 7;
  const int slot  = blk >> 3;          // 0..63
  const int b     = xcd*2 + (slot & 1);
  const int bslot = slot >> 1;         // 0..31
  const int tid   = threadIdx.x;
  const int lane  = tid & 63;
  const int wid   = tid >> 6;          // 0..7

  const float* pb = pos + (size_t)b*SEQ*DIM;
  const float* vb = v   + (size_t)b*SEQ*DIM;
  float* red2 = &S[0][0];              // [8 waves][8 r][64 d] overlay, used post-sync

  for (int t = 0; t < 8; ++t){
    const int r0 = (bslot*8 + t) * 8;  // q-row base for this task

    __syncthreads();                   // red2/S region reuse across iterations
    // ---- stage M (into S region) + q rows ----
    {
      const float4* Mg = (const float4*)(M + (size_t)b*4096);
      float4* Sl = (float4*)&S[0][0];
      Sl[tid]       = Mg[tid];
      Sl[tid + 512] = Mg[tid + 512];
      if (tid < 128){
        const float4* qg = (const float4*)(q + ((size_t)b*SEQ + r0)*DIM);
        ((float4*)&qr[0][0])[tid] = qg[tid];
      }
    }
    __syncthreads();

    // ---- T[8][64] = qr * M (one output per thread) ----
    {
      const float* Ml = &S[0][0];
      const int r = tid >> 6, e = tid & 63;
      float a = 0.f;
      #pragma unroll
      for (int d=0; d<64; ++d)
        a += qr[r][d] * Ml[d*64 + e];
      Tt[r][e] = a;
    }
    __syncthreads();

    // ---- logits S[r][c] = T[r] . pos[c] (4 cols/thread), track row max ----
    float mloc[8];
    #pragma unroll
    for (int r=0;r<8;r++) mloc[r] = -3.0e38f;
    #pragma unroll
    for (int jj=0; jj<2; ++jj){
      const int c0 = tid + 1024*jj;
      const int c1 = c0 + 512;
      float4 pv0[16], pv1[16];
      const float4* pg0 = (const float4*)(pb + (size_t)c0*DIM);
      const float4* pg1 = (const float4*)(pb + (size_t)c1*DIM);
      #pragma unroll
      for (int i=0;i<16;i++){ pv0[i]=pg0[i]; pv1[i]=pg1[i]; }
      #pragma unroll
      for (int r=0;r<8;r++){
        float a0=0.f, a1=0.f;
        #pragma unroll
        for (int d4=0; d4<16; ++d4){
          const float4 tf = *(const float4*)&Tt[r][4*d4];  // wave-uniform broadcast
          a0 += tf.x*pv0[d4].x + tf.y*pv0[d4].y + tf.z*pv0[d4].z + tf.w*pv0[d4].w;
          a1 += tf.x*pv1[d4].x + tf.y*pv1[d4].y + tf.z*pv1[d4].z + tf.w*pv1[d4].w;
        }
        S[r][SW(c0)] = a0;
        S[r][SW(c1)] = a1;
        mloc[r] = fmaxf(mloc[r], fmaxf(a0, a1));
      }
    }

    // ---- row max reduction (8 waves) ----
    #pragma unroll
    for (int r=0;r<8;r++){
      float m = mloc[r];
      #pragma unroll
      for (int off=32; off>0; off>>=1)
        m = fmaxf(m, __shfl_xor(m, off, 64));
      if (lane==0) red[wid][r] = m;
    }
    __syncthreads();
    if (tid < 8){
      float m = red[0][tid];
      #pragma unroll
      for (int w=1;w<8;w++) m = fmaxf(m, red[w][tid]);
      mrow[tid] = m;
    }
    __syncthreads();

    // ---- exp in place + row sums ----
    float mreg[8], sloc[8];
    #pragma unroll
    for (int r=0;r<8;r++){ mreg[r]=mrow[r]; sloc[r]=0.f; }
    #pragma unroll
    for (int j=0;j<4;++j){
      const int cs = SW(tid + 512*j);
      #pragma unroll
      for (int r=0;r<8;r++){
        const float e = __expf(S[r][cs] - mreg[r]);
        S[r][cs] = e;
        sloc[r] += e;
      }
    }
    #pragma unroll
    for (int r=0;r<8;r++){
      float s = sloc[r];
      #pragma unroll
      for (int off=32; off>0; off>>=1)
        s += __shfl_xor(s, off, 64);
      if (lane==0) red[wid][r] = s;
    }
    __syncthreads();
    if (tid < 8){
      float s = red[0][tid];
      #pragma unroll
      for (int w=1;w<8;w++) s += red[w][tid];
      linv[tid] = 1.0f / s;
    }
    __syncthreads();

    // ---- write attn = e * (1/l): nontemporal float4, fully coalesced ----
    float lreg[8];
    #pragma unroll
    for (int r=0;r<8;r++) lreg[r] = linv[r];
    float* ab = attn + ((size_t)b*SEQ + r0)*(size_t)SEQ;
    #pragma unroll
    for (int r=0;r<8;r++){
      const int c = tid*4;              // float4 index == tid
      const int cs = SW(c);             // c%4==0 -> SW(c)+i contiguous
      f32x4 val;
      val.x = S[r][cs  ] * lreg[r];
      val.y = S[r][cs+1] * lreg[r];
      val.z = S[r][cs+2] * lreg[r];
      val.w = S[r][cs+3] * lreg[r];
      __builtin_nontemporal_store(val, (f32x4*)(ab + (size_t)r*SEQ) + tid);
    }

    // ---- PV: out[r][d] = (1/l) sum_c e[r][c] v[c][d] ----
    const int dgrp  = tid & 7;
    const int cpart = tid >> 3;          // 0..63, 32 c's each
    float acc2[8][8];
    #pragma unroll
    for (int r=0;r<8;r++)
      #pragma unroll
      for (int i=0;i<8;i++) acc2[r][i]=0.f;
    for (int ch=0; ch<8; ++ch){
      const int cbase = cpart*32 + ch*4;
      float4 va[4][2];
      #pragma unroll
      for (int i=0;i<4;i++){
        const float* vr = vb + (size_t)(cbase+i)*DIM + dgrp*8;
        va[i][0] = *(const float4*)vr;
        va[i][1] = *(const float4*)(vr+4);
      }
      #pragma unroll
      for (int r=0;r<8;r++){
        const float4 s4 = *(const float4*)&S[r][SW(cbase)];  // conflict-free by SW design
        const float sc[4] = {s4.x, s4.y, s4.z, s4.w};
        #pragma unroll
        for (int i=0;i<4;i++){
          acc2[r][0] += sc[i]*va[i][0].x;
          acc2[r][1] += sc[i]*va[i][0].y;
          acc2[r][2] += sc[i]*va[i][0].z;
          acc2[r][3] += sc[i]*va[i][0].w;
          acc2[r][4] += sc[i]*va[i][1].x;
          acc2[r][5] += sc[i]*va[i][1].y;
          acc2[r][6] += sc[i]*va[i][1].z;
          acc2[r][7] += sc[i]*va[i][1].w;
        }
      }
    }
    // butterfly over the wave's 8 c-partitions (lane bits 3..5), dgrp preserved
    #pragma unroll
    for (int r=0;r<8;r++)
      #pragma unroll
      for (int i=0;i<8;i++){
        float x = acc2[r][i];
        x += __shfl_xor(x, 8, 64);
        x += __shfl_xor(x, 16, 64);
        x += __shfl_xor(x, 32, 64);
        acc2[r][i] = x;
      }
    __syncthreads();                     // all S reads done -> red2 overlay safe
    if (lane < 8){                       // lane == dgrp here
      #pragma unroll
      for (int r=0;r<8;r++)
        #pragma unroll
        for (int i=0;i<8;i++)
          red2[wid*512 + r*64 + lane*8+i] = acc2[r][i];
    }
    __syncthreads();
    {
      const int r = tid >> 6;            // 512 outputs, one per thread
      const int d = tid & 63;
      float s = 0.f;
      #pragma unroll
      for (int w=0;w<8;w++) s += red2[w*512 + r*64 + d];
      float* ob = outp + ((size_t)b*SEQ + r0)*DIM;
      ob[tid] = s * linv[r];
    }
  }
}

extern "C" void kernel_launch(void* const* d_in, const int* in_sizes, int n_in,
                              void* d_out, int out_size, void* d_ws, size_t ws_size,
                              hipStream_t stream){
  const float* q = (const float*)d_in[0];
  const float* k = (const float*)d_in[1];
  const float* v = (const float*)d_in[2];
  const float* p = (const float*)d_in[3];
  float* out  = (float*)d_out;
  float* attn = out + OUT_ELEMS;          // second tuple element
  float* M    = (float*)d_ws;             // 16*64*64 fp32 = 256 KB
  float* part = attn;                     // M-partials scratch; kB overwrites later

  kA1<<<dim3(16,16), 256, 0, stream>>>(k, q, part);
  kA2<<<dim3(256),   256, 0, stream>>>(part, M);
  kB <<<dim3(512),   512, 0, stream>>>(q, p, v, M, out, attn);
}

// Round 4
// 851.071 us; speedup vs baseline: 6.4099x; 6.4099x over previous
//
#include <hip/hip_runtime.h>
#include <cstdint>

#define BH  16
#define SEQ 2048
#define DIM 64
#define OUT_ELEMS (BH*SEQ*DIM)   // 2097152 floats; attn follows at this offset

typedef float f32x4 __attribute__((ext_vector_type(4)));

// XOR swizzle on the S float index: perturb bits 2-4 with bits 5-7.
// Stride-1 wave accesses stay a permutation (conflict-free); the PV phase's
// 64-float c-partitions land 2-way aliased (free per m136).
__device__ __forceinline__ int SW(int c){ return c ^ (((c >> 5) & 7) << 2); }

// ---------------- Kernel A1: partial M = k^T q  (per batch, per 128-row K chunk) ----
__global__ __launch_bounds__(256) void kA1(const float* __restrict__ kk,
                                           const float* __restrict__ qq,
                                           float* __restrict__ part){
  __shared__ __align__(16) float kl[64][68];
  __shared__ __align__(16) float ql[64][68];
  const int b   = blockIdx.y;
  const int ch  = blockIdx.x;          // 16 chunks of 128 rows
  const int tid = threadIdx.x;
  const int j     = tid & 63;
  const int ibase = (tid >> 6) * 16;
  const int lrow  = tid >> 2;
  const int lcol  = (tid & 3) * 16;
  const float* kb = kk + (size_t)b*SEQ*DIM;
  const float* qb = qq + (size_t)b*SEQ*DIM;
  float acc[16];
  #pragma unroll
  for (int i=0;i<16;i++) acc[i]=0.f;
  for (int sub=0; sub<2; ++sub){
    const int l0 = ch*128 + sub*64;
    const float4* ks = (const float4*)(kb + (size_t)(l0+lrow)*DIM + lcol);
    const float4* qs = (const float4*)(qb + (size_t)(l0+lrow)*DIM + lcol);
    float4 kv[4], qv[4];
    #pragma unroll
    for (int i=0;i<4;i++){ kv[i]=ks[i]; qv[i]=qs[i]; }
    __syncthreads();
    #pragma unroll
    for (int i=0;i<4;i++){
      *(float4*)&kl[lrow][lcol+4*i] = kv[i];
      *(float4*)&ql[lrow][lcol+4*i] = qv[i];
    }
    __syncthreads();
    for (int t=0; t<64; ++t){
      const float qv1 = ql[t][j];
      #pragma unroll
      for (int ii=0; ii<16; ++ii)
        acc[ii] += kl[t][ibase+ii] * qv1;
    }
  }
  float* pp = part + (size_t)(b*16+ch)*4096;
  #pragma unroll
  for (int ii=0; ii<16; ++ii)
    pp[(ibase+ii)*64 + j] = acc[ii];
}

// ---------------- Kernel A2: reduce partials, fold 1/temper^2 ----------------------
__global__ __launch_bounds__(256) void kA2(const float* __restrict__ part,
                                           float* __restrict__ M){
  const int idx = blockIdx.x*256 + threadIdx.x;
  const int b = idx >> 12, o = idx & 4095;
  float s = 0.f;
  #pragma unroll
  for (int ch=0; ch<16; ++ch)
    s += part[(size_t)(b*16+ch)*4096 + o];
  M[(size_t)b*4096 + o] = s * (1.0f/64.0f);
}

// ---------------- Kernel C: T[b][row][*] = q[b][row][*] . M[b] -------------------
// Stored in the tail (cols 1984..2047) of attn row (b*SEQ+row); kB consumes it
// before overwriting with the real attn values.
__global__ __launch_bounds__(256) void kC(const float* __restrict__ q,
                                          const float* __restrict__ M,
                                          float* __restrict__ Tdst){
  __shared__ __align__(16) float Ml[4096];
  const int b     = blockIdx.y;
  const int chunk = blockIdx.x;        // 8 chunks x 256 rows
  const int tid   = threadIdx.x;
  {
    const float4* Mg = (const float4*)(M + (size_t)b*4096);
    float4* Sl = (float4*)Ml;
    #pragma unroll
    for (int i=0;i<4;i++) Sl[tid + 256*i] = Mg[tid + 256*i];
  }
  __syncthreads();
  const int e0 = (tid & 7) * 8;
  const int rb = chunk*256 + (tid >> 3);
  for (int s = 0; s < 8; ++s){
    const int row = rb + 32*s;
    const float* qr = q + ((size_t)b*SEQ + row)*DIM;
    float acc[8];
    #pragma unroll
    for (int i=0;i<8;i++) acc[i]=0.f;
    for (int d=0; d<64; ++d){
      const float qd = qr[d];
      #pragma unroll
      for (int i=0;i<8;i++)
        acc[i] += qd * Ml[d*64 + e0 + i];
    }
    float* td = Tdst + ((size_t)b*SEQ + row)*(size_t)SEQ + 1984 + e0;
    *(float4*)td     = *(float4*)&acc[0];
    *(float4*)(td+4) = *(float4*)&acc[4];
  }
}

// ---------------- Kernel B: persistent, XCD-pinned; T via uniform scalar loads ----
__global__ __launch_bounds__(256,2) void kB(const float* __restrict__ pos,
                                            const float* __restrict__ v,
                                            const float* __restrict__ Tsrc,
                                            float* __restrict__ outp,
                                            float* __restrict__ attn){
  __shared__ __align__(16) float S[8][2048];      // 64 KB: logits -> exp values
  __shared__ __align__(16) float red2[4][8][64];  // PV cross-wave partials
  __shared__ float red[4][8];
  __shared__ float mrow[8];
  __shared__ float linv[8];

  const int blk   = blockIdx.x;
  const int xcd   = blk & 7;
  const int slot  = blk >> 3;          // 0..63
  const int b     = xcd*2 + (slot & 1);
  const int bslot = slot >> 1;         // 0..31
  const int tid   = threadIdx.x;
  const int lane  = tid & 63;
  const int wid   = tid >> 6;          // 0..3

  const float* pb = pos + (size_t)b*SEQ*DIM;
  const float* vb = v   + (size_t)b*SEQ*DIM;

  for (int t = 0; t < 8; ++t){
    const int r0 = (bslot*8 + t) * 8;
    const float* Tb = Tsrc + ((size_t)b*SEQ + r0)*(size_t)SEQ + 1984;  // uniform
    __syncthreads();                   // S/red2 reuse across tasks

    // ---- logits S[r][c] = T[r] . pos[c] ; T from SGPRs, pos streamed ----
    float mloc[8];
    #pragma unroll
    for (int r=0;r<8;r++) mloc[r] = -3.0e38f;
    #pragma unroll 1
    for (int j=0;j<8;++j){
      const int c = tid + 256*j;
      const f32x4* pc = (const f32x4*)(pb + (size_t)c*DIM);
      float acc8[8];
      #pragma unroll
      for (int r=0;r<8;r++) acc8[r]=0.f;
      #pragma unroll
      for (int ch=0; ch<8; ++ch){
        const f32x4 a  = pc[2*ch];
        const f32x4 bb = pc[2*ch+1];
        #pragma unroll
        for (int r=0;r<8;r++){
          const float* Ts = Tb + (size_t)r*SEQ + ch*8;   // uniform -> s_load
          acc8[r] += Ts[0]*a.x + Ts[1]*a.y + Ts[2]*a.z + Ts[3]*a.w
                   + Ts[4]*bb.x + Ts[5]*bb.y + Ts[6]*bb.z + Ts[7]*bb.w;
        }
      }
      #pragma unroll
      for (int r=0;r<8;r++){
        S[r][SW(c)] = acc8[r];
        mloc[r] = fmaxf(mloc[r], acc8[r]);
      }
    }

    // ---- row max reduction ----
    #pragma unroll
    for (int r=0;r<8;r++){
      float m = mloc[r];
      #pragma unroll
      for (int off=32; off>0; off>>=1)
        m = fmaxf(m, __shfl_xor(m, off, 64));
      if (lane==0) red[wid][r] = m;
    }
    __syncthreads();
    if (tid < 8)
      mrow[tid] = fmaxf(fmaxf(red[0][tid],red[1][tid]), fmaxf(red[2][tid],red[3][tid]));
    __syncthreads();

    // ---- exp in place + row sums ----
    float mreg[8], sloc[8];
    #pragma unroll
    for (int r=0;r<8;r++){ mreg[r]=mrow[r]; sloc[r]=0.f; }
    for (int j=0;j<8;++j){
      const int cs = SW(tid + 256*j);
      #pragma unroll
      for (int r=0;r<8;r++){
        const float e = __expf(S[r][cs] - mreg[r]);
        S[r][cs] = e;
        sloc[r] += e;
      }
    }
    #pragma unroll
    for (int r=0;r<8;r++){
      float s = sloc[r];
      #pragma unroll
      for (int off=32; off>0; off>>=1)
        s += __shfl_xor(s, off, 64);
      if (lane==0) red[wid][r] = s;
    }
    __syncthreads();
    if (tid < 8)
      linv[tid] = 1.0f / (red[0][tid]+red[1][tid]+red[2][tid]+red[3][tid]);
    __syncthreads();

    // ---- write attn = e * (1/l): nontemporal float4, coalesced ----
    float lreg[8];
    #pragma unroll
    for (int r=0;r<8;r++) lreg[r] = linv[r];
    float* ab = attn + ((size_t)b*SEQ + r0)*(size_t)SEQ;
    #pragma unroll
    for (int r=0;r<8;r++){
      #pragma unroll
      for (int h=0;h<2;h++){
        const int c  = h*1024 + tid*4;
        const int cs = SW(c);
        f32x4 val;
        val.x = S[r][cs  ] * lreg[r];
        val.y = S[r][cs+1] * lreg[r];
        val.z = S[r][cs+2] * lreg[r];
        val.w = S[r][cs+3] * lreg[r];
        __builtin_nontemporal_store(val, (f32x4*)(ab + (size_t)r*SEQ + c));
      }
    }

    // ---- PV: out[r][d] = (1/l) sum_c e[r][c] v[c][d] ----
    const int dgrp  = tid & 7;
    const int cpart = tid >> 3;          // 0..31, 64 c's each
    float acc2[8][8];
    #pragma unroll
    for (int r=0;r<8;r++)
      #pragma unroll
      for (int i=0;i<8;i++) acc2[r][i]=0.f;
    for (int ch=0; ch<16; ++ch){
      const int cbase = cpart*64 + ch*4;
      float4 va[4][2];
      #pragma unroll
      for (int i=0;i<4;i++){
        const float* vr = vb + (size_t)(cbase+i)*DIM + dgrp*8;
        va[i][0] = *(const float4*)vr;
        va[i][1] = *(const float4*)(vr+4);
      }
      #pragma unroll
      for (int r=0;r<8;r++){
        const f32x4 s4 = *(const f32x4*)&S[r][SW(cbase)];
        const float sc[4] = {s4.x, s4.y, s4.z, s4.w};
        #pragma unroll
        for (int i=0;i<4;i++){
          acc2[r][0] += sc[i]*va[i][0].x;
          acc2[r][1] += sc[i]*va[i][0].y;
          acc2[r][2] += sc[i]*va[i][0].z;
          acc2[r][3] += sc[i]*va[i][0].w;
          acc2[r][4] += sc[i]*va[i][1].x;
          acc2[r][5] += sc[i]*va[i][1].y;
          acc2[r][6] += sc[i]*va[i][1].z;
          acc2[r][7] += sc[i]*va[i][1].w;
        }
      }
    }
    #pragma unroll
    for (int r=0;r<8;r++)
      #pragma unroll
      for (int i=0;i<8;i++){
        float x = acc2[r][i];
        x += __shfl_xor(x, 8, 64);
        x += __shfl_xor(x, 16, 64);
        x += __shfl_xor(x, 32, 64);
        acc2[r][i] = x;
      }
    if (lane < 8){                       // lane == dgrp here
      #pragma unroll
      for (int r=0;r<8;r++)
        #pragma unroll
        for (int i=0;i<8;i++)
          red2[wid][r][lane*8+i] = acc2[r][i];
    }
    __syncthreads();
    {
      const int o = tid*2;               // 512 outputs, 2 per thread
      const int r = o >> 6;
      const int d = o & 63;
      const float li = linv[r];
      float2 res;
      res.x = (red2[0][r][d  ]+red2[1][r][d  ]+red2[2][r][d  ]+red2[3][r][d  ]) * li;
      res.y = (red2[0][r][d+1]+red2[1][r][d+1]+red2[2][r][d+1]+red2[3][r][d+1]) * li;
      float* ob = outp + ((size_t)b*SEQ + r0)*DIM;
      *(float2*)(ob + (size_t)r*DIM + d) = res;
    }
  }
}

extern "C" void kernel_launch(void* const* d_in, const int* in_sizes, int n_in,
                              void* d_out, int out_size, void* d_ws, size_t ws_size,
                              hipStream_t stream){
  const float* q = (const float*)d_in[0];
  const float* k = (const float*)d_in[1];
  const float* v = (const float*)d_in[2];
  const float* p = (const float*)d_in[3];
  float* out  = (float*)d_out;
  float* attn = out + OUT_ELEMS;          // second tuple element
  float* M    = (float*)d_ws;             // 16*64*64 fp32 = 256 KB
  float* part = attn;                     // M-partials scratch; dead after kA2

  kA1<<<dim3(16,16), 256, 0, stream>>>(k, q, part);
  kA2<<<dim3(256),   256, 0, stream>>>(part, M);
  kC <<<dim3(8,16),  256, 0, stream>>>(q, M, attn);
  kB <<<dim3(512),   256, 0, stream>>>(p, v, attn, out, attn);
}

// Round 5
// 771.770 us; speedup vs baseline: 7.0686x; 1.1028x over previous
//
#include <hip/hip_runtime.h>
#include <cstdint>

#define BH  16
#define SEQ 2048
#define DIM 64
#define OUT_ELEMS (BH*SEQ*DIM)   // 2097152 floats; attn follows at this offset

typedef float f32x4 __attribute__((ext_vector_type(4)));

// XOR swizzle on the S float index: perturb bits 2-4 with bits 5-7.
// Stride-1 wave accesses stay a permutation (conflict-free); the PV phase's
// 64-float c-partitions land 2-way aliased (free per m136).
__device__ __forceinline__ int SW(int c){ return c ^ (((c >> 5) & 7) << 2); }

// ---------------- Kernel A1: partial M = k^T q  (per batch, per 128-row K chunk) ----
__global__ __launch_bounds__(256) void kA1(const float* __restrict__ kk,
                                           const float* __restrict__ qq,
                                           float* __restrict__ part){
  __shared__ __align__(16) float kl[64][68];   // 68: 16B-aligned rows (68*4=272)
  __shared__ __align__(16) float ql[64][68];
  const int b   = blockIdx.y;
  const int ch  = blockIdx.x;          // 16 chunks of 128 rows
  const int tid = threadIdx.x;
  const int j     = tid & 63;
  const int ibase = (tid >> 6) * 16;   // wave-uniform
  const int lrow  = tid >> 2;
  const int lcol  = (tid & 3) * 16;
  const float* kb = kk + (size_t)b*SEQ*DIM;
  const float* qb = qq + (size_t)b*SEQ*DIM;
  float acc[16];
  #pragma unroll
  for (int i=0;i<16;i++) acc[i]=0.f;
  for (int sub=0; sub<2; ++sub){
    const int l0 = ch*128 + sub*64;
    const float4* ks = (const float4*)(kb + (size_t)(l0+lrow)*DIM + lcol);
    const float4* qs = (const float4*)(qb + (size_t)(l0+lrow)*DIM + lcol);
    float4 kv[4], qv[4];
    #pragma unroll
    for (int i=0;i<4;i++){ kv[i]=ks[i]; qv[i]=qs[i]; }
    __syncthreads();
    #pragma unroll
    for (int i=0;i<4;i++){
      *(float4*)&kl[lrow][lcol+4*i] = kv[i];
      *(float4*)&ql[lrow][lcol+4*i] = qv[i];
    }
    __syncthreads();
    for (int t=0; t<64; ++t){
      const float qv1 = ql[t][j];
      const f32x4 k0 = *(const f32x4*)&kl[t][ibase];      // broadcast (uniform addr)
      const f32x4 k1 = *(const f32x4*)&kl[t][ibase+4];
      const f32x4 k2 = *(const f32x4*)&kl[t][ibase+8];
      const f32x4 k3 = *(const f32x4*)&kl[t][ibase+12];
      acc[0]+=k0.x*qv1; acc[1]+=k0.y*qv1; acc[2]+=k0.z*qv1; acc[3]+=k0.w*qv1;
      acc[4]+=k1.x*qv1; acc[5]+=k1.y*qv1; acc[6]+=k1.z*qv1; acc[7]+=k1.w*qv1;
      acc[8]+=k2.x*qv1; acc[9]+=k2.y*qv1; acc[10]+=k2.z*qv1; acc[11]+=k2.w*qv1;
      acc[12]+=k3.x*qv1; acc[13]+=k3.y*qv1; acc[14]+=k3.z*qv1; acc[15]+=k3.w*qv1;
    }
  }
  float* pp = part + (size_t)(b*16+ch)*4096;
  #pragma unroll
  for (int ii=0; ii<16; ++ii)
    pp[(ibase+ii)*64 + j] = acc[ii];
}

// ---------------- Kernel A2: reduce partials, fold 1/temper^2 ----------------------
__global__ __launch_bounds__(256) void kA2(const float* __restrict__ part,
                                           float* __restrict__ M){
  const int idx = blockIdx.x*256 + threadIdx.x;
  const int b = idx >> 12, o = idx & 4095;
  float s = 0.f;
  #pragma unroll
  for (int ch=0; ch<16; ++ch)
    s += part[(size_t)(b*16+ch)*4096 + o];
  M[(size_t)b*4096 + o] = s * (1.0f/64.0f);
}

// ---------------- Kernel C: T[b][row][*] = q[b][row][*] . M[b] -------------------
// Stored in the tail (cols 1984..2047) of attn row (b*SEQ+row); kB consumes it
// before overwriting with the real attn values.
__global__ __launch_bounds__(256) void kC(const float* __restrict__ q,
                                          const float* __restrict__ M,
                                          float* __restrict__ Tdst){
  __shared__ __align__(16) float Ml[4096];
  const int b     = blockIdx.y;
  const int chunk = blockIdx.x;        // 16 chunks x 128 rows
  const int tid   = threadIdx.x;
  {
    const f32x4* Mg = (const f32x4*)(M + (size_t)b*4096);
    f32x4* Sl = (f32x4*)Ml;
    #pragma unroll
    for (int i=0;i<4;i++) Sl[tid + 256*i] = Mg[tid + 256*i];
  }
  __syncthreads();
  const int e0 = (tid & 7) * 8;
  #pragma unroll 1
  for (int s = 0; s < 4; ++s){
    const int row = chunk*128 + (tid >> 3) + 32*s;
    const f32x4* qr = (const f32x4*)(q + ((size_t)b*SEQ + row)*DIM);
    f32x4 qv[16];
    #pragma unroll
    for (int i=0;i<16;i++) qv[i] = qr[i];
    float acc[8];
    #pragma unroll
    for (int i=0;i<8;i++) acc[i]=0.f;
    #pragma unroll
    for (int d4=0; d4<16; ++d4){
      const float qd[4] = {qv[d4].x, qv[d4].y, qv[d4].z, qv[d4].w};
      #pragma unroll
      for (int u=0; u<4; ++u){
        const int d = d4*4+u;
        const f32x4 m0 = *(const f32x4*)&Ml[d*64+e0];
        const f32x4 m1 = *(const f32x4*)&Ml[d*64+e0+4];
        acc[0]+=qd[u]*m0.x; acc[1]+=qd[u]*m0.y; acc[2]+=qd[u]*m0.z; acc[3]+=qd[u]*m0.w;
        acc[4]+=qd[u]*m1.x; acc[5]+=qd[u]*m1.y; acc[6]+=qd[u]*m1.z; acc[7]+=qd[u]*m1.w;
      }
    }
    float* td = Tdst + ((size_t)b*SEQ + row)*(size_t)SEQ + 1984 + e0;
    *(f32x4*)td     = *(f32x4*)&acc[0];
    *(f32x4*)(td+4) = *(f32x4*)&acc[4];
  }
}

// ---------------- Kernel B: persistent, XCD-pinned; T in LDS, reg-blocked logits --
__global__ __launch_bounds__(256,2) void kB(const float* __restrict__ pos,
                                            const float* __restrict__ v,
                                            const float* __restrict__ Tsrc,
                                            float* __restrict__ outp,
                                            float* __restrict__ attn){
  __shared__ __align__(16) float S[8][2048];      // 64 KB: logits -> exp; red2 overlay
  __shared__ __align__(16) float Tl[8][64];       // T for this task
  __shared__ float red[4][8];
  __shared__ float mrow[8];
  __shared__ float linv[8];

  const int blk   = blockIdx.x;
  const int xcd   = blk & 7;
  const int slot  = blk >> 3;          // 0..63
  const int b     = xcd*2 + (slot & 1);
  const int bslot = slot >> 1;         // 0..31
  const int tid   = threadIdx.x;
  const int lane  = tid & 63;
  const int wid   = tid >> 6;          // 0..3

  const float* pb = pos + (size_t)b*SEQ*DIM;
  const float* vb = v   + (size_t)b*SEQ*DIM;
  float* red2 = &S[0][0];              // [4 waves][8 r][64 d] overlay, post-sync

  for (int t = 0; t < 8; ++t){
    const int r0 = (bslot*8 + t) * 8;

    __syncthreads();                   // prev task's S/red2 reads done
    // ---- stage T[8][64] from attn-row tails ----
    if (tid < 128){
      const int r  = tid >> 4;
      const int e4 = (tid & 15) * 4;
      const float* ts = Tsrc + ((size_t)b*SEQ + r0 + r)*(size_t)SEQ + 1984 + e4;
      *(f32x4*)&Tl[r][e4] = *(const f32x4*)ts;
    }
    __syncthreads();

    // ---- logits: ch-outer, T chunk in VGPR (LDS broadcast), j+1 pos prefetch ----
    float accA[4][8], accB[4][8];
    #pragma unroll
    for (int j=0;j<4;j++)
      #pragma unroll
      for (int r=0;r<8;r++){ accA[j][r]=0.f; accB[j][r]=0.f; }

    #pragma unroll 1
    for (int ch=0; ch<8; ++ch){
      f32x4 t0[8], t1[8];
      #pragma unroll
      for (int r=0;r<8;r++){
        t0[r] = *(const f32x4*)&Tl[r][ch*8];     // same addr all lanes -> broadcast
        t1[r] = *(const f32x4*)&Tl[r][ch*8+4];
      }
      const float* pA0 = pb + (size_t)tid*DIM + ch*8;
      f32x4 a0 = *(const f32x4*)pA0;
      f32x4 a1 = *(const f32x4*)(pA0+4);
      f32x4 b0 = *(const f32x4*)(pA0 + 1024*DIM);
      f32x4 b1 = *(const f32x4*)(pA0 + 1024*DIM + 4);
      #pragma unroll
      for (int j=0;j<4;++j){
        f32x4 na0,na1,nb0,nb1;
        if (j<3){
          const float* pA = pb + (size_t)(tid+256*(j+1))*DIM + ch*8;
          na0 = *(const f32x4*)pA;
          na1 = *(const f32x4*)(pA+4);
          nb0 = *(const f32x4*)(pA + 1024*DIM);
          nb1 = *(const f32x4*)(pA + 1024*DIM + 4);
        }
        #pragma unroll
        for (int r=0;r<8;r++){
          accA[j][r] += t0[r].x*a0.x + t0[r].y*a0.y + t0[r].z*a0.z + t0[r].w*a0.w
                      + t1[r].x*a1.x + t1[r].y*a1.y + t1[r].z*a1.z + t1[r].w*a1.w;
          accB[j][r] += t0[r].x*b0.x + t0[r].y*b0.y + t0[r].z*b0.z + t0[r].w*b0.w
                      + t1[r].x*b1.x + t1[r].y*b1.y + t1[r].z*b1.z + t1[r].w*b1.w;
        }
        a0=na0; a1=na1; b0=nb0; b1=nb1;
      }
    }

    // ---- write S + per-thread row max ----
    float mloc[8];
    #pragma unroll
    for (int r=0;r<8;r++) mloc[r] = -3.0e38f;
    #pragma unroll
    for (int j=0;j<4;++j){
      const int cA = tid + 256*j;
      const int cB = cA + 1024;
      const int sA = SW(cA), sB = SW(cB);
      #pragma unroll
      for (int r=0;r<8;r++){
        S[r][sA] = accA[j][r];
        S[r][sB] = accB[j][r];
        mloc[r] = fmaxf(mloc[r], fmaxf(accA[j][r], accB[j][r]));
      }
    }

    // ---- row max reduction ----
    #pragma unroll
    for (int r=0;r<8;r++){
      float m = mloc[r];
      #pragma unroll
      for (int off=32; off>0; off>>=1)
        m = fmaxf(m, __shfl_xor(m, off, 64));
      if (lane==0) red[wid][r] = m;
    }
    __syncthreads();
    if (tid < 8)
      mrow[tid] = fmaxf(fmaxf(red[0][tid],red[1][tid]), fmaxf(red[2][tid],red[3][tid]));
    __syncthreads();

    // ---- exp in place (b128) + row sums ----
    float mreg[8], sloc[8];
    #pragma unroll
    for (int r=0;r<8;r++){ mreg[r]=mrow[r]; sloc[r]=0.f; }
    #pragma unroll
    for (int h=0; h<2; ++h){
      const int cs = SW(tid*4 + 1024*h);
      #pragma unroll
      for (int r=0;r<8;r++){
        f32x4 e4 = *(f32x4*)&S[r][cs];
        e4.x = __expf(e4.x - mreg[r]);
        e4.y = __expf(e4.y - mreg[r]);
        e4.z = __expf(e4.z - mreg[r]);
        e4.w = __expf(e4.w - mreg[r]);
        *(f32x4*)&S[r][cs] = e4;
        sloc[r] += e4.x + e4.y + e4.z + e4.w;
      }
    }
    #pragma unroll
    for (int r=0;r<8;r++){
      float s = sloc[r];
      #pragma unroll
      for (int off=32; off>0; off>>=1)
        s += __shfl_xor(s, off, 64);
      if (lane==0) red[wid][r] = s;
    }
    __syncthreads();
    if (tid < 8)
      linv[tid] = 1.0f / (red[0][tid]+red[1][tid]+red[2][tid]+red[3][tid]);
    __syncthreads();

    // ---- write attn = e * (1/l): nontemporal b128, coalesced ----
    float lreg[8];
    #pragma unroll
    for (int r=0;r<8;r++) lreg[r] = linv[r];
    float* ab = attn + ((size_t)b*SEQ + r0)*(size_t)SEQ;
    #pragma unroll
    for (int h=0;h<2;h++){
      const int c  = h*1024 + tid*4;
      const int cs = SW(c);
      #pragma unroll
      for (int r=0;r<8;r++){
        f32x4 val = *(f32x4*)&S[r][cs];
        val.x *= lreg[r]; val.y *= lreg[r]; val.z *= lreg[r]; val.w *= lreg[r];
        __builtin_nontemporal_store(val, (f32x4*)(ab + (size_t)r*SEQ + c));
      }
    }

    // ---- PV: out[r][d] = (1/l) sum_c e[r][c] v[c][d]; v double-buffered ----
    const int dgrp  = tid & 7;
    const int cpart = tid >> 3;          // 0..31, 64 c's each
    float acc2[8][8];
    #pragma unroll
    for (int r=0;r<8;r++)
      #pragma unroll
      for (int i=0;i<8;i++) acc2[r][i]=0.f;
    f32x4 va0[4], va1[4];
    #pragma unroll
    for (int i=0;i<4;i++){
      const float* vr = vb + (size_t)(cpart*64+i)*DIM + dgrp*8;
      va0[i] = *(const f32x4*)vr;
      va1[i] = *(const f32x4*)(vr+4);
    }
    #pragma unroll 1
    for (int ch=0; ch<16; ++ch){
      const int cbase = cpart*64 + ch*4;
      f32x4 w0[4], w1[4];
      if (ch < 15){
        #pragma unroll
        for (int i=0;i<4;i++){
          const float* vr = vb + (size_t)(cbase+4+i)*DIM + dgrp*8;
          w0[i] = *(const f32x4*)vr;
          w1[i] = *(const f32x4*)(vr+4);
        }
      }
      #pragma unroll
      for (int r=0;r<8;r++){
        const f32x4 s4 = *(const f32x4*)&S[r][SW(cbase)];
        const float sc[4] = {s4.x, s4.y, s4.z, s4.w};
        #pragma unroll
        for (int i=0;i<4;i++){
          acc2[r][0] += sc[i]*va0[i].x;
          acc2[r][1] += sc[i]*va0[i].y;
          acc2[r][2] += sc[i]*va0[i].z;
          acc2[r][3] += sc[i]*va0[i].w;
          acc2[r][4] += sc[i]*va1[i].x;
          acc2[r][5] += sc[i]*va1[i].y;
          acc2[r][6] += sc[i]*va1[i].z;
          acc2[r][7] += sc[i]*va1[i].w;
        }
      }
      #pragma unroll
      for (int i=0;i<4;i++){ va0[i]=w0[i]; va1[i]=w1[i]; }
    }
    #pragma unroll
    for (int r=0;r<8;r++)
      #pragma unroll
      for (int i=0;i<8;i++){
        float x = acc2[r][i];
        x += __shfl_xor(x, 8, 64);
        x += __shfl_xor(x, 16, 64);
        x += __shfl_xor(x, 32, 64);
        acc2[r][i] = x;
      }
    __syncthreads();                     // all S reads done -> red2 overlay safe
    if (lane < 8){                       // lane == dgrp here
      #pragma unroll
      for (int r=0;r<8;r++)
        #pragma unroll
        for (int i=0;i<8;i++)
          red2[wid*512 + r*64 + lane*8+i] = acc2[r][i];
    }
    __syncthreads();
    {
      const int o = tid*2;               // 512 outputs, 2 per thread
      const int r = o >> 6;
      const int d = o & 63;
      const float li = linv[r];
      float2 res;
      res.x = (red2[0*512+r*64+d  ]+red2[1*512+r*64+d  ]+red2[2*512+r*64+d  ]+red2[3*512+r*64+d  ]) * li;
      res.y = (red2[0*512+r*64+d+1]+red2[1*512+r*64+d+1]+red2[2*512+r*64+d+1]+red2[3*512+r*64+d+1]) * li;
      float* ob = outp + ((size_t)b*SEQ + r0)*DIM;
      *(float2*)(ob + (size_t)r*DIM + d) = res;
    }
  }
}

extern "C" void kernel_launch(void* const* d_in, const int* in_sizes, int n_in,
                              void* d_out, int out_size, void* d_ws, size_t ws_size,
                              hipStream_t stream){
  const float* q = (const float*)d_in[0];
  const float* k = (const float*)d_in[1];
  const float* v = (const float*)d_in[2];
  const float* p = (const float*)d_in[3];
  float* out  = (float*)d_out;
  float* attn = out + OUT_ELEMS;          // second tuple element
  float* M    = (float*)d_ws;             // 16*64*64 fp32 = 256 KB
  float* part = attn;                     // M-partials scratch; dead after kA2

  kA1<<<dim3(16,16), 256, 0, stream>>>(k, q, part);
  kA2<<<dim3(256),   256, 0, stream>>>(part, M);
  kC <<<dim3(16,16), 256, 0, stream>>>(q, M, attn);
  kB <<<dim3(512),   256, 0, stream>>>(p, v, attn, out, attn);
}

// Round 6
// 613.104 us; speedup vs baseline: 8.8978x; 1.2588x over previous
//
#include <hip/hip_runtime.h>
#include <cstdint>

#define BH  16
#define SEQ 2048
#define DIM 64
#define OUT_ELEMS (BH*SEQ*DIM)   // 2097152 floats; attn follows at this offset

typedef float f32x4 __attribute__((ext_vector_type(4)));
typedef float f32x2 __attribute__((ext_vector_type(2)));
typedef short bf16x8 __attribute__((ext_vector_type(8)));
typedef unsigned short u16;
typedef unsigned short u16x4 __attribute__((ext_vector_type(4)));

#define MFMA16 __builtin_amdgcn_mfma_f32_16x16x32_bf16

// ---- dynamic LDS partition (floats) ----
#define SROW      2052                    // 2048 + 4 pad -> bank spread
#define VTM_OFF   (16*SROW)               // union: M fp32[64][64] | vT bf16[64][136]
#define TL_OFF    (VTM_OFF + 4352)        // T fp32[16][64]
#define QS_OFF    (TL_OFF + 1024)         // q fp32[16][64]
#define RED_OFF   (QS_OFF + 1024)         // red[8][16] + mrow[16] + linv[16]
#define LDS_FLOATS (RED_OFF + 160)
#define LDS_BYTES  (LDS_FLOATS*4)         // 157568 B -> 1 block/CU

__device__ __forceinline__ u16 f2bf(float x){            // RNE f32->bf16
  uint32_t u = __float_as_uint(x);
  return (u16)((u + 0x7fffu + ((u>>16)&1u)) >> 16);
}
__device__ __forceinline__ void split8(f32x4 a, f32x4 b, bf16x8& hi, bf16x8& lo){
  float v[8] = {a.x,a.y,a.z,a.w,b.x,b.y,b.z,b.w};
  #pragma unroll
  for (int i=0;i<8;i++){
    uint32_t u  = __float_as_uint(v[i]);
    uint32_t hb = u & 0xffff0000u;
    hi[i] = (short)(hb>>16);
    lo[i] = (short)f2bf(v[i] - __uint_as_float(hb));
  }
}
__device__ __forceinline__ bf16x8 pack8(f32x4 a, f32x4 b){
  bf16x8 r;
  r[0]=(short)f2bf(a.x); r[1]=(short)f2bf(a.y); r[2]=(short)f2bf(a.z); r[3]=(short)f2bf(a.w);
  r[4]=(short)f2bf(b.x); r[5]=(short)f2bf(b.y); r[6]=(short)f2bf(b.z); r[7]=(short)f2bf(b.w);
  return r;
}

// ---------------- Kernel A1: partial M = k^T q (per batch, per 128-row chunk) ------
__global__ __launch_bounds__(256) void kA1(const float* __restrict__ kk,
                                           const float* __restrict__ qq,
                                           float* __restrict__ part){
  __shared__ __align__(16) float kl[64][68];
  __shared__ __align__(16) float ql[64][68];
  const int b   = blockIdx.y;
  const int ch  = blockIdx.x;
  const int tid = threadIdx.x;
  const int j     = tid & 63;
  const int ibase = (tid >> 6) * 16;   // wave-uniform
  const int lrow  = tid >> 2;
  const int lcol  = (tid & 3) * 16;
  const float* kb = kk + (size_t)b*SEQ*DIM;
  const float* qb = qq + (size_t)b*SEQ*DIM;
  float acc[16];
  #pragma unroll
  for (int i=0;i<16;i++) acc[i]=0.f;
  for (int sub=0; sub<2; ++sub){
    const int l0 = ch*128 + sub*64;
    const f32x4* ks = (const f32x4*)(kb + (size_t)(l0+lrow)*DIM + lcol);
    const f32x4* qs = (const f32x4*)(qb + (size_t)(l0+lrow)*DIM + lcol);
    f32x4 kv[4], qv[4];
    #pragma unroll
    for (int i=0;i<4;i++){ kv[i]=ks[i]; qv[i]=qs[i]; }
    __syncthreads();
    #pragma unroll
    for (int i=0;i<4;i++){
      *(f32x4*)&kl[lrow][lcol+4*i] = kv[i];
      *(f32x4*)&ql[lrow][lcol+4*i] = qv[i];
    }
    __syncthreads();
    for (int t=0; t<64; ++t){
      const float qv1 = ql[t][j];
      const f32x4 k0 = *(const f32x4*)&kl[t][ibase];
      const f32x4 k1 = *(const f32x4*)&kl[t][ibase+4];
      const f32x4 k2 = *(const f32x4*)&kl[t][ibase+8];
      const f32x4 k3 = *(const f32x4*)&kl[t][ibase+12];
      acc[0]+=k0.x*qv1; acc[1]+=k0.y*qv1; acc[2]+=k0.z*qv1; acc[3]+=k0.w*qv1;
      acc[4]+=k1.x*qv1; acc[5]+=k1.y*qv1; acc[6]+=k1.z*qv1; acc[7]+=k1.w*qv1;
      acc[8]+=k2.x*qv1; acc[9]+=k2.y*qv1; acc[10]+=k2.z*qv1; acc[11]+=k2.w*qv1;
      acc[12]+=k3.x*qv1; acc[13]+=k3.y*qv1; acc[14]+=k3.z*qv1; acc[15]+=k3.w*qv1;
    }
  }
  float* pp = part + (size_t)(b*16+ch)*4096;
  #pragma unroll
  for (int ii=0; ii<16; ++ii)
    pp[(ibase+ii)*64 + j] = acc[ii];
}

// ---------------- Kernel A2: reduce partials, fold 1/temper^2 ----------------------
__global__ __launch_bounds__(256) void kA2(const float* __restrict__ part,
                                           float* __restrict__ M){
  const int idx = blockIdx.x*256 + threadIdx.x;
  const int b = idx >> 12, o = idx & 4095;
  float s = 0.f;
  #pragma unroll
  for (int ch=0; ch<16; ++ch)
    s += part[(size_t)(b*16+ch)*4096 + o];
  M[(size_t)b*4096 + o] = s * (1.0f/64.0f);
}

// ---------------- Kernel B: MFMA persistent kernel --------------------------------
// grid 256 (1 block/CU, 32/XCD), 512 threads, task = 16 q-rows, 8 tasks/block.
__global__ __launch_bounds__(512,2) void kB(const float* __restrict__ q,
                                            const float* __restrict__ pos,
                                            const float* __restrict__ v,
                                            const float* __restrict__ M,
                                            float* __restrict__ outp,
                                            float* __restrict__ attn){
  extern __shared__ __align__(16) float smem[];
  float* S    = smem;                        // [16][SROW] logits->exp, then Pfrag overlay
  float* VTM  = smem + VTM_OFF;              // M fp32 | vT bf16[64][136]
  u16*   vT   = (u16*)VTM;
  float* Tl   = smem + TL_OFF;               // [16][64]
  float* qs   = smem + QS_OFF;               // [16][64]
  float* red  = smem + RED_OFF;              // [8][16]
  float* mrow = red + 128;                   // [16]
  float* linv = mrow + 16;                   // [16]

  const int blk   = blockIdx.x;
  const int xcd   = blk & 7;
  const int slot  = blk >> 3;                // 0..31
  const int b     = xcd*2 + (slot & 1);
  const int bslot = slot >> 1;               // 0..15
  const int tid   = threadIdx.x;
  const int lane  = tid & 63;
  const int w     = tid >> 6;                // 0..7
  const int quad  = lane >> 4;
  const int l16   = lane & 15;

  const float* pb = pos + (size_t)b*SEQ*DIM;
  const float* vb = v   + (size_t)b*SEQ*DIM;
  const float* qb = q   + (size_t)b*SEQ*DIM;
  const float* Mb = M   + (size_t)b*4096;

  for (int t = 0; t < 8; ++t){
    const int r0 = (bslot*8 + t) * 16;
    __syncthreads();                          // prev task fully done (S/vT reuse)

    // ---- stage M + q rows ----
    {
      const f32x4* Mg = (const f32x4*)Mb;
      f32x4* Md = (f32x4*)VTM;
      Md[tid]     = Mg[tid];
      Md[tid+512] = Mg[tid+512];
      if (tid < 256)
        ((f32x4*)qs)[tid] = ((const f32x4*)(qb + (size_t)r0*DIM))[tid];
    }
    __syncthreads();

    // ---- T[16][64] = qs * M (2 outputs/thread) ----
    {
      const int r = tid >> 5;                 // 0..15
      const int e = tid & 31;
      float a0 = 0.f, a1 = 0.f;
      #pragma unroll 8
      for (int d=0; d<64; ++d){
        const float qd = qs[r*64 + d];
        a0 += qd * VTM[d*64 + e];
        a1 += qd * VTM[d*64 + e + 32];
      }
      Tl[r*64 + e]      = a0;
      Tl[r*64 + e + 32] = a1;
    }
    __syncthreads();

    // ---- A-frags (T hi/lo) for both k-halves ----
    bf16x8 Ah[2], Al[2];
    #pragma unroll
    for (int h=0; h<2; ++h){
      const float* ts = &Tl[l16*64 + h*32 + quad*8];
      split8(*(const f32x4*)ts, *(const f32x4*)(ts+4), Ah[h], Al[h]);
    }

    // ---- logits: wave w covers c in [w*256, w*256+256), 16-c tiles, MFMA ----
    #pragma unroll 2
    for (int tt=0; tt<16; ++tt){
      const int c0 = w*256 + tt*16;
      const float* pr = pb + (size_t)(c0 + l16)*DIM + quad*8;
      f32x4 p0 = *(const f32x4*)pr;
      f32x4 p1 = *(const f32x4*)(pr+4);
      f32x4 p2 = *(const f32x4*)(pr+32);
      f32x4 p3 = *(const f32x4*)(pr+36);
      bf16x8 Bh0, Bl0, Bh1, Bl1;
      split8(p0, p1, Bh0, Bl0);
      split8(p2, p3, Bh1, Bl1);
      f32x4 acc = {0.f,0.f,0.f,0.f};
      acc = MFMA16(Ah[0], Bh0, acc, 0,0,0);
      acc = MFMA16(Al[0], Bh0, acc, 0,0,0);
      acc = MFMA16(Ah[0], Bl0, acc, 0,0,0);
      acc = MFMA16(Ah[1], Bh1, acc, 0,0,0);
      acc = MFMA16(Al[1], Bh1, acc, 0,0,0);
      acc = MFMA16(Ah[1], Bl1, acc, 0,0,0);
      #pragma unroll
      for (int i=0;i<4;i++)
        S[(quad*4+i)*SROW + c0 + l16] = acc[i];
    }
    __syncthreads();

    // ---- row max (r = tid&15, seg = tid>>4) ----
    {
      const int r = tid & 15, seg = tid >> 4;
      const f32x4* sr = (const f32x4*)&S[r*SROW + seg*64];
      float m = -3.0e38f;
      #pragma unroll
      for (int i=0;i<16;i++){
        const f32x4 x = sr[i];
        m = fmaxf(m, fmaxf(fmaxf(x.x,x.y), fmaxf(x.z,x.w)));
      }
      m = fmaxf(m, __shfl_xor(m, 16, 64));
      m = fmaxf(m, __shfl_xor(m, 32, 64));
      if (lane < 16) red[w*16 + lane] = m;
    }
    __syncthreads();
    if (tid < 16){
      float m = red[tid];
      #pragma unroll
      for (int w2=1; w2<8; ++w2) m = fmaxf(m, red[w2*16 + tid]);
      mrow[tid] = m;
    }
    __syncthreads();

    // ---- exp in place + row sums ----
    {
      const int r = tid & 15, seg = tid >> 4;
      const float mr = mrow[r];
      f32x4* sr = (f32x4*)&S[r*SROW + seg*64];
      float s = 0.f;
      #pragma unroll
      for (int i=0;i<16;i++){
        f32x4 x = sr[i];
        x.x = __expf(x.x - mr); x.y = __expf(x.y - mr);
        x.z = __expf(x.z - mr); x.w = __expf(x.w - mr);
        sr[i] = x;
        s += x.x + x.y + x.z + x.w;
      }
      s += __shfl_xor(s, 16, 64);
      s += __shfl_xor(s, 32, 64);
      if (lane < 16) red[w*16 + lane] = s;
    }
    __syncthreads();
    if (tid < 16){
      float s = red[tid];
      #pragma unroll
      for (int w2=1; w2<8; ++w2) s += red[w2*16 + tid];
      linv[tid] = 1.0f / s;
    }
    __syncthreads();

    // ---- attn = e * linv : NT b128, coalesced ----
    {
      const int r  = tid >> 5;                // 0..15
      const int cq = (tid & 31) * 4;
      const float li = linv[r];
      float* ab = attn + ((size_t)b*SEQ + r0 + r)*(size_t)SEQ;
      const float* sr = &S[r*SROW];
      #pragma unroll
      for (int j=0;j<16;++j){
        const int c = cq + 128*j;
        f32x4 val = *(const f32x4*)(sr + c);
        val.x *= li; val.y *= li; val.z *= li; val.w *= li;
        __builtin_nontemporal_store(val, (f32x4*)(ab + c));
      }
    }

    // ---- PV: out[16][64] += e(bf16) x v(bf16), vT staged per 128-c tile ----
    f32x4 pacc0 = {0.f,0.f,0.f,0.f}, pacc1 = {0.f,0.f,0.f,0.f};
    const int kch   = w >> 1;                 // k-chunk within tile (0..3)
    const int npair = w & 1;                  // n-tiles {2np, 2np+1}
    for (int vt=0; vt<16; ++vt){
      __syncthreads();                        // vT reuse / first-iter M-region reuse
      {   // stage v[vt*128 .. +128)[64] -> vT[d][136] bf16 transposed
        const int c4 = (tid & 31)*4;
        const int d4 = (tid >> 5)*4;
        const int cg = vt*128 + c4;
        f32x4 r0v = *(const f32x4*)(vb + (size_t)(cg  )*DIM + d4);
        f32x4 r1v = *(const f32x4*)(vb + (size_t)(cg+1)*DIM + d4);
        f32x4 r2v = *(const f32x4*)(vb + (size_t)(cg+2)*DIM + d4);
        f32x4 r3v = *(const f32x4*)(vb + (size_t)(cg+3)*DIM + d4);
        const float rr[4][4] = {{r0v.x,r1v.x,r2v.x,r3v.x},
                                {r0v.y,r1v.y,r2v.y,r3v.y},
                                {r0v.z,r1v.z,r2v.z,r3v.z},
                                {r0v.w,r1v.w,r2v.w,r3v.w}};
        #pragma unroll
        for (int dd=0; dd<4; ++dd){
          u16x4 pk;
          pk[0]=f2bf(rr[dd][0]); pk[1]=f2bf(rr[dd][1]);
          pk[2]=f2bf(rr[dd][2]); pk[3]=f2bf(rr[dd][3]);
          *(u16x4*)&vT[(d4+dd)*136 + c4] = pk;
        }
      }
      __syncthreads();
      {   // A-frag from S (e), B-frags from vT
        const int cbase = kch*32;
        const float* es = &S[l16*SROW + vt*128 + cbase + quad*8];
        const bf16x8 Af = pack8(*(const f32x4*)es, *(const f32x4*)(es+4));
        const int n0 = (npair*2)*16 + l16;
        const int n1 = n0 + 16;
        const bf16x8 B0 = *(const bf16x8*)&vT[n0*136 + cbase + quad*8];
        const bf16x8 B1 = *(const bf16x8*)&vT[n1*136 + cbase + quad*8];
        pacc0 = MFMA16(Af, B0, pacc0, 0,0,0);
        pacc1 = MFMA16(Af, B1, pacc1, 0,0,0);
      }
    }
    __syncthreads();                          // PV MFMAs + attn S-reads done
    {   // Pfrag overlay into S: slot = (w*2 + ntl)
      float* Pf = S;
      #pragma unroll
      for (int i=0;i<4;i++){
        Pf[(w*2+0)*256 + (quad*4+i)*16 + l16] = pacc0[i];
        Pf[(w*2+1)*256 + (quad*4+i)*16 + l16] = pacc1[i];
      }
      pacc0 = (f32x4){0.f,0.f,0.f,0.f};
      pacc1 = (f32x4){0.f,0.f,0.f,0.f};
    }
    __syncthreads();
    {   // reduce over 4 k-waves, scale, write out (2 floats/thread)
      const int o = tid*2;
      const int m = o >> 6;
      const int d = o & 63;
      const int nt = d >> 4;
      float s0 = 0.f, s1 = 0.f;
      #pragma unroll
      for (int kk=0; kk<4; ++kk){
        const int sl = (2*kk + (nt>>1))*2 + (nt&1);
        s0 += S[sl*256 + m*16 + (d&15)];
        s1 += S[sl*256 + m*16 + (d&15) + 1];
      }
      const float li = linv[m];
      f32x2 res; res.x = s0*li; res.y = s1*li;
      *(f32x2*)(outp + ((size_t)b*SEQ + r0 + m)*DIM + d) = res;
    }
  }
}

extern "C" void kernel_launch(void* const* d_in, const int* in_sizes, int n_in,
                              void* d_out, int out_size, void* d_ws, size_t ws_size,
                              hipStream_t stream){
  const float* q = (const float*)d_in[0];
  const float* k = (const float*)d_in[1];
  const float* v = (const float*)d_in[2];
  const float* p = (const float*)d_in[3];
  float* out  = (float*)d_out;
  float* attn = out + OUT_ELEMS;          // second tuple element
  float* M    = (float*)d_ws;             // 16*64*64 fp32 = 256 KB
  float* part = attn;                     // M-partials scratch; dead after kA2

  static int lds_set = 0;
  (void)lds_set;
  hipFuncSetAttribute((const void*)kB,
                      hipFuncAttributeMaxDynamicSharedMemorySize, LDS_BYTES);

  kA1<<<dim3(16,16), 256, 0, stream>>>(k, q, part);
  kA2<<<dim3(256),   256, 0, stream>>>(part, M);
  kB <<<dim3(256),   512, LDS_BYTES, stream>>>(q, p, v, M, out, attn);
}